// Round 5
// baseline (814.256 us; speedup 1.0000x reference)
//
#include <hip/hip_runtime.h>
#include <math.h>

#define NB 4
#define NC 128
#define NO 64
#define HH 512
#define WW 512
#define PH 64
#define PW 64
#define PHW (PH*PW)   // 4096

// ---------------- zero psum accumulator ----------------
__global__ void zero_psum(float* __restrict__ psum) {
    psum[threadIdx.x] = 0.f;   // 512 threads, 512 entries
}

// ---------------- 8x8 max pool + fused per-(b,c) sum ----------------
// One thread per HALF pooled cell (4 contiguous floats x 8 rows).
// Every load instruction covers a dense 1KB (64 lanes x contiguous 16B).
// Lane pairs combine via shfl_xor to finish the 8-wide cell.
__global__ __launch_bounds__(256) void pool8(const float* __restrict__ x,
                                             float* __restrict__ p,
                                             float* __restrict__ psum) {
    int q  = blockIdx.x * 256 + threadIdx.x;   // over NB*NC*PH*PW*2 half-cells
    int wh = q & 127;                          // 128 half-cells per pooled row
    int h  = (q >> 7) & (PH - 1);
    int bc = q >> 13;                          // uniform per block (8192 | block span)
    const float* src = x + ((size_t)bc * HH + (size_t)h * 8) * WW + (size_t)wh * 4;
    float m = -INFINITY;
#pragma unroll
    for (int r = 0; r < 8; ++r) {
        float4 a = *(const float4*)(src + (size_t)r * WW);
        m = fmaxf(m, fmaxf(fmaxf(a.x, a.y), fmaxf(a.z, a.w)));
    }
    float mm = fmaxf(m, __shfl_xor(m, 1, 64));  // full 8x8 cell max (both lanes hold it)
    if (!(threadIdx.x & 1)) p[q >> 1] = mm;

    // block partial sum of pooled values (count each cell once: even lanes)
    float ps = (threadIdx.x & 1) ? 0.f : mm;
#pragma unroll
    for (int off = 32; off > 0; off >>= 1) ps += __shfl_down(ps, off, 64);
    __shared__ float ls[4];
    int lane = threadIdx.x & 63, wid = threadIdx.x >> 6;
    if (lane == 0) ls[wid] = ps;
    __syncthreads();
    if (threadIdx.x == 0) atomicAdd(&psum[bc], ls[0] + ls[1] + ls[2] + ls[3]);
}

// ---- attn[b,o,hw] = vmean[b,o] * (sum_c p[b,c,hw]*Wk[o,c] + bk[o]),
//      vmean[b,o] = (sum_c psum[b,c]*Wv[o,c])/4096 + bv[o]  (computed in-block)
__global__ __launch_bounds__(256) void attn_k(const float* __restrict__ p,
                                              const float* __restrict__ Wk,
                                              const float* __restrict__ bk,
                                              const float* __restrict__ Wv,
                                              const float* __restrict__ bv,
                                              const float* __restrict__ psum,
                                              float* __restrict__ attn) {
    int blk = blockIdx.x;
    int hwblk = blk & 15;                // 16 hw chunks of 256
    int ot    = (blk >> 4) & 3;          // 4 o-tiles of 16
    int b     = blk >> 6;                // 4 batches
    int hw    = hwblk * 256 + threadIdx.x;
    int obase = ot * 16;

    __shared__ float vm[16];
    if (threadIdx.x < 16) {
        int oo = obase + threadIdx.x;
        float s = 0.f;
        for (int c = 0; c < NC; ++c)
            s = fmaf(psum[b * NC + c], Wv[oo * NC + c], s);
        vm[threadIdx.x] = s * (1.f / (float)PHW) + bv[oo];
    }
    __syncthreads();

    const float* pb = p + (size_t)b * NC * PHW + hw;
    float acc[16];
#pragma unroll
    for (int o = 0; o < 16; ++o) acc[o] = 0.f;
    for (int c = 0; c < NC; ++c) {
        float val = pb[(size_t)c * PHW];
#pragma unroll
        for (int o = 0; o < 16; ++o)
            acc[o] = fmaf(val, Wk[(obase + o) * NC + c], acc[o]);
    }
#pragma unroll
    for (int o = 0; o < 16; ++o) {
        int oo = obase + o;
        attn[((size_t)(b * NO + oo)) * PHW + hw] = vm[o] * (acc[o] + bk[oo]);
    }
}

// ---------------- bilinear x8 upsample, one thread per SOURCE cell ------
// x8 with align_corners=False: within a cell the 8 fractional weights are the
// constants (2j+9)&15 / 16. Thread loads 3+3 neighbors, emits 8 outputs.
__global__ __launch_bounds__(256) void upsample_k(const float* __restrict__ attn,
                                                  float* __restrict__ out) {
    int t  = blockIdx.x * 256 + threadIdx.x;   // over NB*NO*512*64
    int k  = t & 63;                           // source column cell
    int y  = (t >> 6) & 511;                   // output row
    int bo = t >> 15;                          // 0..255
    int m  = y >> 3;
    int i  = y & 7;
    int ylo = (i < 4) ? m - 1 : m;
    int r0 = max(ylo, 0);
    int r1 = min(ylo + 1, PH - 1);
    float fy = (float)((2 * i + 9) & 15) * 0.0625f;

    const float* base = attn + (size_t)bo * PHW;
    const float* row0 = base + r0 * PW;
    const float* row1 = base + r1 * PW;
    int xm1 = max(k - 1, 0);
    int xp1 = min(k + 1, PW - 1);
    float a0 = row0[xm1], a1 = row0[k], a2 = row0[xp1];
    float b0 = row1[xm1], b1 = row1[k], b2 = row1[xp1];
    // row-blend first (fy uniform per thread), then x-lerp with constant fx
    float c0 = a0 + fy * (b0 - a0);
    float c1 = a1 + fy * (b1 - a1);
    float c2 = a2 + fy * (b2 - a2);
    float d01 = c1 - c0;
    float d12 = c2 - c1;
    float4 lo, hi;
    lo.x = c0 + (9.f  * 0.0625f) * d01;
    lo.y = c0 + (11.f * 0.0625f) * d01;
    lo.z = c0 + (13.f * 0.0625f) * d01;
    lo.w = c0 + (15.f * 0.0625f) * d01;
    hi.x = c1 + (1.f  * 0.0625f) * d12;
    hi.y = c1 + (3.f  * 0.0625f) * d12;
    hi.z = c1 + (5.f  * 0.0625f) * d12;
    hi.w = c1 + (7.f  * 0.0625f) * d12;
    float* dst = out + ((size_t)bo * HH + y) * WW + (size_t)k * 8;
    *(float4*)dst = lo;
    *(float4*)(dst + 4) = hi;
}

extern "C" void kernel_launch(void* const* d_in, const int* in_sizes, int n_in,
                              void* d_out, int out_size, void* d_ws, size_t ws_size,
                              hipStream_t stream) {
    const float* x  = (const float*)d_in[0];
    const float* Wk = (const float*)d_in[1];
    const float* bk = (const float*)d_in[2];
    const float* Wv = (const float*)d_in[3];
    const float* bv = (const float*)d_in[4];
    float* out = (float*)d_out;

    float* p     = (float*)d_ws;                    // NB*NC*PHW = 8 MB
    float* attn  = p + (size_t)NB * NC * PHW;       // NB*NO*PHW = 4 MB
    float* psum  = attn + (size_t)NB * NO * PHW;    // 512 f

    zero_psum<<<1, 512, 0, stream>>>(psum);
    pool8<<<NB * NC * PHW * 2 / 256, 256, 0, stream>>>(x, p, psum);
    attn_k<<<256, 256, 0, stream>>>(p, Wk, bk, Wv, bv, psum, attn);
    upsample_k<<<NB * NO * HH * PW / 256, 256, 0, stream>>>(attn, out);
}